// Round 1
// baseline (211.672 us; speedup 1.0000x reference)
//
#include <hip/hip_runtime.h>
#include <hip/hip_bf16.h>

#define BATCH 64
#define MDIM 512
#define NDIM 1024
#define KDIM 1024

#define BM 128
#define BN 128
#define BK 32
#define NT (KDIM / BK)      // 32 K-steps
#define LDST 40             // LDS row stride in bf16 elems (80 B = 20 banks, 16B-aligned)

typedef __attribute__((ext_vector_type(4))) float f32x4;
typedef __attribute__((ext_vector_type(8))) short bf16x8;
typedef __attribute__((ext_vector_type(4))) unsigned int u32x4;

// fp32 -> bf16 RNE, two at a time, packed into one dword
__device__ __forceinline__ unsigned int pack2_bf16(float lo, float hi) {
    unsigned int ulo = __float_as_uint(lo);
    unsigned int uhi = __float_as_uint(hi);
    ulo += 0x7fffu + ((ulo >> 16) & 1u);
    uhi += 0x7fffu + ((uhi >> 16) & 1u);
    return (uhi & 0xffff0000u) | (ulo >> 16);
}

__global__ __launch_bounds__(256, 2)
void grouped_fc_kernel(const float* __restrict__ X,
                       const float* __restrict__ W,
                       const float* __restrict__ Bias,
                       float* __restrict__ Out) {
    const int tile = blockIdx.x;   // 0..31  (4 M-tiles x 8 N-tiles)
    const int bidx = blockIdx.y;   // 0..63  batch
    const int tm = tile & 3;
    const int tn = tile >> 2;

    const int tid  = threadIdx.x;
    const int lane = tid & 63;
    const int wid  = tid >> 6;     // 0..3
    const int wm   = wid & 1;      // wave row (2)
    const int wn   = wid >> 1;     // wave col (2)

    __shared__ unsigned short ldsA[2][BM][LDST];
    __shared__ unsigned short ldsB[2][BN][LDST];

    const float* srcA = X + ((size_t)bidx * MDIM + (size_t)tm * BM) * KDIM;
    const float* srcB = W + ((size_t)bidx * NDIM + (size_t)tn * BN) * KDIM;

    // staging geometry: per tile, 512 groups of 8 floats (128 rows x 4 groups);
    // thread handles groups {tid, tid+256}
    int s_row[2], s_col[2];
#pragma unroll
    for (int g = 0; g < 2; ++g) {
        int flat = tid + g * 256;
        s_row[g] = flat >> 2;
        s_col[g] = (flat & 3) * 8;
    }

    f32x4 va[2][2], vb[2][2];

    auto load_tiles = [&](int kt) {
#pragma unroll
        for (int g = 0; g < 2; ++g) {
            const float* pa = srcA + (size_t)s_row[g] * KDIM + kt * BK + s_col[g];
            va[g][0] = *(const f32x4*)(pa);
            va[g][1] = *(const f32x4*)(pa + 4);
            const float* pb = srcB + (size_t)s_row[g] * KDIM + kt * BK + s_col[g];
            vb[g][0] = *(const f32x4*)(pb);
            vb[g][1] = *(const f32x4*)(pb + 4);
        }
    };

    auto store_tiles = [&](int buf) {
#pragma unroll
        for (int g = 0; g < 2; ++g) {
            u32x4 wa, wb;
            wa[0] = pack2_bf16(va[g][0][0], va[g][0][1]);
            wa[1] = pack2_bf16(va[g][0][2], va[g][0][3]);
            wa[2] = pack2_bf16(va[g][1][0], va[g][1][1]);
            wa[3] = pack2_bf16(va[g][1][2], va[g][1][3]);
            wb[0] = pack2_bf16(vb[g][0][0], vb[g][0][1]);
            wb[1] = pack2_bf16(vb[g][0][2], vb[g][0][3]);
            wb[2] = pack2_bf16(vb[g][1][0], vb[g][1][1]);
            wb[3] = pack2_bf16(vb[g][1][2], vb[g][1][3]);
            *(u32x4*)&ldsA[buf][s_row[g]][s_col[g]] = wa;
            *(u32x4*)&ldsB[buf][s_row[g]][s_col[g]] = wb;
        }
    };

    const int frow = lane & 15;          // row (A) / col (B) within 16x16 fragment
    const int fk   = (lane >> 4) * 8;    // K offset of this lane's 8 elems

    f32x4 acc[4][4];
#pragma unroll
    for (int mi = 0; mi < 4; ++mi)
#pragma unroll
        for (int ni = 0; ni < 4; ++ni)
            acc[mi][ni] = (f32x4){0.f, 0.f, 0.f, 0.f};

    // prologue: stage K-tile 0
    load_tiles(0);
    store_tiles(0);

    int cur = 0;
#pragma unroll 1
    for (int kt = 0; kt < NT; ++kt) {
        __syncthreads();                 // buf[cur] ready for all waves
        const bool more = (kt + 1 < NT);
        if (more) load_tiles(kt + 1);    // issue next-tile global loads early

        bf16x8 af[4], bfr[4];
#pragma unroll
        for (int mi = 0; mi < 4; ++mi)
            af[mi] = *(const bf16x8*)&ldsA[cur][wm * 64 + mi * 16 + frow][fk];
#pragma unroll
        for (int ni = 0; ni < 4; ++ni)
            bfr[ni] = *(const bf16x8*)&ldsB[cur][wn * 64 + ni * 16 + frow][fk];

#pragma unroll
        for (int mi = 0; mi < 4; ++mi)
#pragma unroll
            for (int ni = 0; ni < 4; ++ni)
                acc[mi][ni] = __builtin_amdgcn_mfma_f32_16x16x32_bf16(
                    af[mi], bfr[ni], acc[mi][ni], 0, 0, 0);

        if (more) store_tiles(cur ^ 1);  // write next tile into the other buffer
        cur ^= 1;
    }

    // epilogue: acc layout col=lane&15, row=(lane>>4)*4+r  (m89-verified)
#pragma unroll
    for (int ni = 0; ni < 4; ++ni) {
        const int gc = tn * BN + wn * 64 + ni * 16 + frow;
        const float bv = Bias[bidx * NDIM + gc];
#pragma unroll
        for (int mi = 0; mi < 4; ++mi) {
            const int gr0 = tm * BM + wm * 64 + mi * 16 + (lane >> 4) * 4;
            float* po = Out + ((size_t)bidx * MDIM + gr0) * NDIM + gc;
#pragma unroll
            for (int r = 0; r < 4; ++r)
                po[(size_t)r * NDIM] = acc[mi][ni][r] + bv;
        }
    }
}

extern "C" void kernel_launch(void* const* d_in, const int* in_sizes, int n_in,
                              void* d_out, int out_size, void* d_ws, size_t ws_size,
                              hipStream_t stream) {
    const float* X  = (const float*)d_in[0];
    const float* W  = (const float*)d_in[1];
    const float* Bs = (const float*)d_in[2];
    float* Out = (float*)d_out;

    dim3 grid(32, BATCH);   // 4x8 tiles per batch, 64 batches = 2048 blocks
    grouped_fc_kernel<<<grid, 256, 0, stream>>>(X, W, Bs, Out);
}

// Round 3
// 156.382 us; speedup vs baseline: 1.3536x; 1.3536x over previous
//
#include <hip/hip_runtime.h>
#include <hip/hip_bf16.h>

#define BATCH 64
#define MDIM 512
#define NDIM 1024
#define KDIM 1024

#define BM 256
#define BN 256
#define BK 32
#define NT (KDIM / BK)      // 32 K-steps

typedef __attribute__((ext_vector_type(4))) float f32x4;
typedef __attribute__((ext_vector_type(8))) short bf16x8;
typedef __attribute__((ext_vector_type(4))) unsigned int u32x4;

// fp32 pair -> packed bf16x2 (RNE); emits v_cvt_pk_bf16_f32
__device__ __forceinline__ unsigned int cvt2(float lo, float hi) {
    __hip_bfloat162 h = __float22bfloat162_rn(float2{lo, hi});
    return *(unsigned int*)&h;
}

__global__ __launch_bounds__(512, 2)
void grouped_fc_kernel(const float* __restrict__ X,
                       const float* __restrict__ W,
                       const float* __restrict__ Bias,
                       float* __restrict__ Out) {
    // XCD swizzle (bijective: 512 % 8 == 0): XCD j gets batches [8j, 8j+8),
    // batch-major so a batch's 8 tiles are co-resident on one XCD's L2.
    const int swz  = (blockIdx.x & 7) * 64 + (blockIdx.x >> 3);
    const int bidx = swz >> 3;     // 0..63 batch
    const int tile = swz & 7;      // 0..7  (2 M-tiles x 4 N-tiles)
    const int tm = tile & 1;
    const int tn = tile >> 1;

    const int tid  = threadIdx.x;
    const int lane = tid & 63;
    const int wid  = tid >> 6;     // 0..7
    const int wm   = wid & 1;      // 2 wave rows (128 out-rows each)
    const int wn   = wid >> 1;     // 4 wave cols (64 out-cols each)

    // [row][32] bf16, 64 B/row; 16B-slot s stored at s ^ ((row>>1)&3)
    __shared__ unsigned short ldsA[2][BM][BK];
    __shared__ unsigned short ldsB[2][BN][BK];

    const float* srcA = X + ((size_t)bidx * MDIM + (size_t)tm * BM) * KDIM;
    const float* srcB = W + ((size_t)bidx * NDIM + (size_t)tn * BN) * KDIM;

    // staging geometry: 1024 slots of 8 floats per tile (256 rows x 4 slots);
    // thread handles slots {tid, tid+512} of A and of B
    int s_row[2], s_c[2], s_sw[2];
#pragma unroll
    for (int g = 0; g < 2; ++g) {
        int f = tid + g * 512;
        s_row[g] = f >> 2;
        s_c[g]   = (f & 3) * 8;                           // float offset in row
        s_sw[g]  = ((f & 3) ^ ((s_row[g] >> 1) & 3)) * 8; // swizzled elem offset
    }

    f32x4 va[2][2], vb[2][2];

    auto load_tiles = [&](int kt) {
#pragma unroll
        for (int g = 0; g < 2; ++g) {
            const float* pa = srcA + (size_t)s_row[g] * KDIM + kt * BK + s_c[g];
            va[g][0] = *(const f32x4*)(pa);
            va[g][1] = *(const f32x4*)(pa + 4);
            const float* pb = srcB + (size_t)s_row[g] * KDIM + kt * BK + s_c[g];
            vb[g][0] = *(const f32x4*)(pb);
            vb[g][1] = *(const f32x4*)(pb + 4);
        }
    };

    auto store_tiles = [&](int buf) {
#pragma unroll
        for (int g = 0; g < 2; ++g) {
            u32x4 wa, wb;
            wa[0] = cvt2(va[g][0][0], va[g][0][1]);
            wa[1] = cvt2(va[g][0][2], va[g][0][3]);
            wa[2] = cvt2(va[g][1][0], va[g][1][1]);
            wa[3] = cvt2(va[g][1][2], va[g][1][3]);
            wb[0] = cvt2(vb[g][0][0], vb[g][0][1]);
            wb[1] = cvt2(vb[g][0][2], vb[g][0][3]);
            wb[2] = cvt2(vb[g][1][0], vb[g][1][1]);
            wb[3] = cvt2(vb[g][1][2], vb[g][1][3]);
            *(u32x4*)&ldsA[buf][s_row[g]][s_sw[g]] = wa;
            *(u32x4*)&ldsB[buf][s_row[g]][s_sw[g]] = wb;
        }
    };

    const int frow = lane & 15;      // row within 16x16 frag (bases 16-aligned)
    const int rsl  = ((lane >> 4) ^ ((frow >> 1) & 3)) * 8;  // swizzled read slot

    f32x4 acc[8][4];
#pragma unroll
    for (int mi = 0; mi < 8; ++mi)
#pragma unroll
        for (int ni = 0; ni < 4; ++ni)
            acc[mi][ni] = (f32x4){0.f, 0.f, 0.f, 0.f};

    // prologue: tile 0 -> regs -> LDS buf0; tile 1 loads in flight
    load_tiles(0);
    store_tiles(0);
    load_tiles(1);

#pragma unroll 2
    for (int kt = 0; kt < NT; ++kt) {
        const int cur = kt & 1;
        // Force-drain our LDS writes before signaling the barrier (release
        // side insurance — do not rely on the compiler's pre-barrier drain).
        asm volatile("s_waitcnt lgkmcnt(0)" ::: "memory");
        __builtin_amdgcn_sched_barrier(0);
        __syncthreads();                   // buf[cur] fully written, all reads of buf[cur^1] consumed

        // store-early: tile kt+1 (regs, loaded last iter) -> buf[cur^1];
        // overlaps with the MFMA phase below instead of serializing before
        // the next barrier.
        if (kt + 1 < NT) store_tiles(cur ^ 1);
        // issue tile kt+2 global loads; they land during MFMA + next barrier
        if (kt + 2 < NT) load_tiles(kt + 2);

        bf16x8 af[8], bfr[4];
#pragma unroll
        for (int mi = 0; mi < 8; ++mi)
            af[mi] = *(const bf16x8*)&ldsA[cur][wm * 128 + mi * 16 + frow][rsl];
#pragma unroll
        for (int ni = 0; ni < 4; ++ni)
            bfr[ni] = *(const bf16x8*)&ldsB[cur][wn * 64 + ni * 16 + frow][rsl];

#pragma unroll
        for (int mi = 0; mi < 8; ++mi)
#pragma unroll
            for (int ni = 0; ni < 4; ++ni)
                acc[mi][ni] = __builtin_amdgcn_mfma_f32_16x16x32_bf16(
                    af[mi], bfr[ni], acc[mi][ni], 0, 0, 0);
    }

    // epilogue: acc layout col=lane&15, row=(lane>>4)*4+r (m89-verified)
#pragma unroll
    for (int ni = 0; ni < 4; ++ni) {
        const int gc = tn * BN + wn * 64 + ni * 16 + frow;
        const float bv = Bias[bidx * NDIM + gc];
#pragma unroll
        for (int mi = 0; mi < 8; ++mi) {
            const int gr0 = tm * BM + wm * 128 + mi * 16 + (lane >> 4) * 4;
            float* po = Out + ((size_t)bidx * MDIM + gr0) * NDIM + gc;
#pragma unroll
            for (int r = 0; r < 4; ++r)
                po[(size_t)r * NDIM] = acc[mi][ni][r] + bv;
        }
    }
}

extern "C" void kernel_launch(void* const* d_in, const int* in_sizes, int n_in,
                              void* d_out, int out_size, void* d_ws, size_t ws_size,
                              hipStream_t stream) {
    const float* X  = (const float*)d_in[0];
    const float* W  = (const float*)d_in[1];
    const float* Bs = (const float*)d_in[2];
    float* Out = (float*)d_out;

    grouped_fc_kernel<<<dim3(512), dim3(512), 0, stream>>>(X, W, Bs, Out);
}